// Round 1
// baseline (2002.122 us; speedup 1.0000x reference)
//
#include <hip/hip_runtime.h>
#include <hip/hip_bf16.h>

#define N_NODES 30000
#define N_EDGES 480000
#define F_IN 376
#define HID 512
#define DENSE_F 1536
#define NHEADS 20   // 4 (gat1) + 16 (gat2)

// ---------------------------------------------------------------------------
// Stage 0: degree / count histograms (edge-parallel, atomics on scalars only)
// ---------------------------------------------------------------------------
__global__ __launch_bounds__(256) void build_stats(
    const int* __restrict__ dst, const float* __restrict__ ew,
    float* __restrict__ deg, int* __restrict__ cnt)
{
    int e = blockIdx.x * 256 + threadIdx.x;
    if (e >= N_EDGES) return;
    int t = dst[e];
    atomicAdd(&deg[t], ew[e]);
    atomicAdd(&cnt[t], 1);
}

__global__ __launch_bounds__(256) void node_stats(
    float* __restrict__ deg, float* __restrict__ dinv)
{
    int i = blockIdx.x * 256 + threadIdx.x;
    if (i >= N_NODES) return;
    float d = deg[i] + 1.0f;           // self-loop weight 1
    deg[i] = d;                        // deg > 0 always
    dinv[i] = rsqrtf(d);
}

// single-block exclusive scan of cnt -> rowptr (and woff copy)
__global__ __launch_bounds__(1024) void scan_rowptr(
    const int* __restrict__ cnt, int* __restrict__ rowptr, int* __restrict__ woff)
{
    __shared__ int temp[1024];
    __shared__ int carry;
    int t = threadIdx.x;
    if (t == 0) carry = 0;
    __syncthreads();
    for (int base = 0; base < N_NODES; base += 1024) {
        int i = base + t;
        int v = (i < N_NODES) ? cnt[i] : 0;
        temp[t] = v;
        __syncthreads();
        for (int off = 1; off < 1024; off <<= 1) {
            int add = (t >= off) ? temp[t - off] : 0;
            __syncthreads();
            temp[t] += add;
            __syncthreads();
        }
        int excl = temp[t] - v;
        if (i < N_NODES) { rowptr[i] = carry + excl; woff[i] = carry + excl; }
        __syncthreads();
        if (t == 1023) carry += temp[1023];
        __syncthreads();
    }
    if (t == 0) rowptr[N_NODES] = carry;   // == E
}

__global__ __launch_bounds__(256) void scatter_csr(
    const int* __restrict__ src, const int* __restrict__ dst,
    const float* __restrict__ ew, int* __restrict__ woff,
    int* __restrict__ col, float* __restrict__ wcsr)
{
    int e = blockIdx.x * 256 + threadIdx.x;
    if (e >= N_EDGES) return;
    int t = dst[e];
    int p = atomicAdd(&woff[t], 1);
    col[p] = src[e];
    wcsr[p] = ew[e];
}

// ---------------------------------------------------------------------------
// fp32 tiled GEMM: C[M x 512] = A[M x K] * B[K x 512]  (+C if beta1)
// 64x64 tile, 256 threads, 4x4 per thread.
// ---------------------------------------------------------------------------
__global__ __launch_bounds__(256) void sgemm_nn(
    const float* __restrict__ A, int lda,
    const float* __restrict__ B, int ldb,
    float* __restrict__ C, int ldc,
    int M, int K, int beta1)
{
    __shared__ float As[16][68];
    __shared__ float Bs[16][68];
    const int tid = threadIdx.x;
    const int tx = tid & 15;     // col group (4 cols each)
    const int ty = tid >> 4;     // row group (4 rows each)
    const int row0 = blockIdx.y * 64;
    const int col0 = blockIdx.x * 64;
    const int akk = tid & 15;    // A-load: k within tile
    const int am  = tid >> 4;    // A-load: row base
    const int bn  = tid & 63;    // B-load: col
    const int bk  = tid >> 6;    // B-load: k base
    float acc[4][4] = {};
    for (int k0 = 0; k0 < K; k0 += 16) {
#pragma unroll
        for (int p = 0; p < 4; ++p) {
            int m = am + p * 16;
            int row = row0 + m;
            int k = k0 + akk;
            As[akk][m] = (row < M && k < K) ? A[(long)row * lda + k] : 0.f;
        }
#pragma unroll
        for (int p = 0; p < 4; ++p) {
            int kk = bk + p * 4;
            int k = k0 + kk;
            Bs[kk][bn] = (k < K) ? B[(long)k * ldb + col0 + bn] : 0.f;
        }
        __syncthreads();
#pragma unroll
        for (int kk = 0; kk < 16; ++kk) {
            float a[4], b[4];
#pragma unroll
            for (int r = 0; r < 4; ++r) a[r] = As[kk][ty * 4 + r];
#pragma unroll
            for (int c = 0; c < 4; ++c) b[c] = Bs[kk][tx * 4 + c];
#pragma unroll
            for (int r = 0; r < 4; ++r)
#pragma unroll
                for (int c = 0; c < 4; ++c)
                    acc[r][c] = fmaf(a[r], b[c], acc[r][c]);
        }
        __syncthreads();
    }
#pragma unroll
    for (int r = 0; r < 4; ++r) {
        int row = row0 + ty * 4 + r;
        if (row < M) {
            float* cp = C + (long)row * ldc + col0 + tx * 4;
            if (beta1) {
#pragma unroll
                for (int c = 0; c < 4; ++c) cp[c] += acc[r][c];
            } else {
                float4 v = make_float4(acc[r][0], acc[r][1], acc[r][2], acc[r][3]);
                *reinterpret_cast<float4*>(cp) = v;
            }
        }
    }
}

// ---------------------------------------------------------------------------
// GCN aggregation: out[i] = relu( h[i]/deg[i] + sum_e dinv[s]*w*dinv[i]*h[s] + b )
// one block (128 threads, float4 each) per destination node, CSR, no atomics
// ---------------------------------------------------------------------------
__global__ __launch_bounds__(128) void gcn_agg(
    const float* __restrict__ h, const int* __restrict__ rowptr,
    const int* __restrict__ col, const float* __restrict__ wcsr,
    const float* __restrict__ dinv, const float* __restrict__ deg,
    const float* __restrict__ bias, float* __restrict__ out, int ldout)
{
    int i = blockIdx.x;
    int c = threadIdx.x * 4;
    float4 acc = *reinterpret_cast<const float4*>(h + (long)i * HID + c);
    float selfw = 1.0f / deg[i];                 // dinv[i]*1*dinv[i]
    acc.x *= selfw; acc.y *= selfw; acc.z *= selfw; acc.w *= selfw;
    float di = dinv[i];
    int e0 = rowptr[i], e1 = rowptr[i + 1];
    for (int e = e0; e < e1; ++e) {
        int s = col[e];
        float nw = dinv[s] * wcsr[e] * di;
        float4 hv = *reinterpret_cast<const float4*>(h + (long)s * HID + c);
        acc.x = fmaf(nw, hv.x, acc.x);
        acc.y = fmaf(nw, hv.y, acc.y);
        acc.z = fmaf(nw, hv.z, acc.z);
        acc.w = fmaf(nw, hv.w, acc.w);
    }
    float4 b = *reinterpret_cast<const float4*>(bias + c);
    float4 o;
    o.x = fmaxf(acc.x + b.x, 0.f);
    o.y = fmaxf(acc.y + b.y, 0.f);
    o.z = fmaxf(acc.z + b.z, 0.f);
    o.w = fmaxf(acc.w + b.w, 0.f);
    *reinterpret_cast<float4*>(out + (long)i * ldout + c) = o;
}

// SAGE mean aggregation: mean[i] = (sum_e x1[s]) / max(cnt,1)
__global__ __launch_bounds__(128) void sage_mean(
    const float* __restrict__ x1, int ldx, const int* __restrict__ rowptr,
    const int* __restrict__ col, const int* __restrict__ cnt,
    float* __restrict__ mean)
{
    int i = blockIdx.x;
    int c = threadIdx.x * 4;
    float4 acc = make_float4(0.f, 0.f, 0.f, 0.f);
    int e0 = rowptr[i], e1 = rowptr[i + 1];
    for (int e = e0; e < e1; ++e) {
        int s = col[e];
        float4 hv = *reinterpret_cast<const float4*>(x1 + (long)s * ldx + c);
        acc.x += hv.x; acc.y += hv.y; acc.z += hv.z; acc.w += hv.w;
    }
    float inv = 1.0f / fmaxf((float)cnt[i], 1.0f);
    acc.x *= inv; acc.y *= inv; acc.z *= inv; acc.w *= inv;
    *reinterpret_cast<float4*>(mean + (long)i * HID + c) = acc;
}

// x3 = relu(h + sage_b) -> dense cols [1024,1536)
__global__ __launch_bounds__(256) void sage_finish(
    const float* __restrict__ h, const float* __restrict__ bias,
    float* __restrict__ out /* dense + 1024 */)
{
    int tid = blockIdx.x * 256 + threadIdx.x;
    if (tid >= N_NODES * HID) return;
    int i = tid >> 9;
    int c = tid & (HID - 1);
    float v = h[tid] + bias[c];
    out[(long)i * DENSE_F + c] = fmaxf(v, 0.f);
}

// pack gat1_W [1536,4] + gat2_W [1536,16] -> Wg [1536,20]; pack a_src/a_dst
__global__ __launch_bounds__(256) void pack_gat(
    const float* __restrict__ g1W, const float* __restrict__ g2W,
    const float* __restrict__ a1s, const float* __restrict__ a1d,
    const float* __restrict__ a2s, const float* __restrict__ a2d,
    float* __restrict__ Wg, float* __restrict__ asrc, float* __restrict__ adst)
{
    int tid = blockIdx.x * 256 + threadIdx.x;
    if (tid < DENSE_F * NHEADS) {
        int k = tid / NHEADS, hh = tid % NHEADS;
        Wg[tid] = (hh < 4) ? g1W[k * 4 + hh] : g2W[k * 16 + (hh - 4)];
    } else if (tid < DENSE_F * NHEADS + NHEADS) {
        int hh = tid - DENSE_F * NHEADS;
        asrc[hh] = (hh < 4) ? a1s[hh] : a2s[hh - 4];
        adst[hh] = (hh < 4) ? a1d[hh] : a2d[hh - 4];
    }
}

// hgat[i,h] = dense[i,:] . Wg[:,h]   (thread = i*20+h)
__global__ __launch_bounds__(256) void gat_linear(
    const float* __restrict__ dense, const float* __restrict__ Wg,
    float* __restrict__ hgat)
{
    int tid = blockIdx.x * 256 + threadIdx.x;
    if (tid >= N_NODES * NHEADS) return;
    int i = tid / NHEADS;
    int hh = tid % NHEADS;
    const float* drow = dense + (long)i * DENSE_F;
    float acc = 0.f;
#pragma unroll 8
    for (int k = 0; k < DENSE_F; ++k)
        acc = fmaf(drow[k], Wg[k * NHEADS + hh], acc);
    hgat[tid] = acc;
}

// per-dst attention: softmax over incoming edges (+self loop), no max-shift
// (|e| <= ~1 so exp is safe; softmax is shift-invariant vs the reference)
__global__ __launch_bounds__(64) void gat_agg(
    const float* __restrict__ hgat, const int* __restrict__ rowptr,
    const int* __restrict__ col, const float* __restrict__ asrc,
    const float* __restrict__ adst, const float* __restrict__ b1p,
    const float* __restrict__ b2p, float* __restrict__ xout)
{
    int i = blockIdx.x;
    int lane = threadIdx.x;
    int h = (lane < NHEADS) ? lane : 0;
    float hg_i = hgat[(long)i * NHEADS + h];
    float as = asrc[h], ad = adst[h];
    float adhg = ad * hg_i;
    // self loop
    float ev = hg_i * as + adhg;
    ev = ev > 0.f ? ev : 0.2f * ev;
    float ex = __expf(ev);
    float den = ex, og = ex * hg_i;
    int e0 = rowptr[i], e1 = rowptr[i + 1];
    for (int e = e0; e < e1; ++e) {
        int s = col[e];
        float hs = hgat[(long)s * NHEADS + h];
        float t = fmaf(hs, as, adhg);
        t = t > 0.f ? t : 0.2f * t;
        float x = __expf(t);
        den += x;
        og = fmaf(x, hs, og);
    }
    float out = (lane < NHEADS) ? og / den : 0.f;
    // sum groups of 4: lanes {0-3}=gat1 heads, {4-19}=gat2 heads
    float s4 = out + __shfl_xor(out, 1);
    s4 += __shfl_xor(s4, 2);
    float g0 = __shfl(s4, 0);
    float g1 = __shfl(s4, 4);
    float g2 = __shfl(s4, 8);
    float g3 = __shfl(s4, 12);
    float g4 = __shfl(s4, 16);
    if (lane == 0) {
        float a1 = g0 * 0.25f + b1p[0];
        float a2 = (g1 + g2 + g3 + g4) * 0.0625f + b2p[0];
        xout[i] = 0.5f * (a1 + a2);
    }
}

// ---------------------------------------------------------------------------
extern "C" void kernel_launch(void* const* d_in, const int* in_sizes, int n_in,
                              void* d_out, int out_size, void* d_ws, size_t ws_size,
                              hipStream_t stream) {
    (void)in_sizes; (void)n_in; (void)out_size; (void)ws_size;
    const float* x        = (const float*)d_in[0];
    const int*   ei       = (const int*)d_in[1];
    const float* ew       = (const float*)d_in[2];
    const float* W1       = (const float*)d_in[3];
    const float* b1       = (const float*)d_in[4];
    const float* W2       = (const float*)d_in[5];
    const float* b2       = (const float*)d_in[6];
    const float* sWl      = (const float*)d_in[7];
    const float* sWr      = (const float*)d_in[8];
    const float* sb       = (const float*)d_in[9];
    const float* g1W      = (const float*)d_in[10];
    const float* g1as     = (const float*)d_in[11];
    const float* g1ad     = (const float*)d_in[12];
    const float* g1b      = (const float*)d_in[13];
    const float* g2W      = (const float*)d_in[14];
    const float* g2as     = (const float*)d_in[15];
    const float* g2ad     = (const float*)d_in[16];
    const float* g2b      = (const float*)d_in[17];

    const int* src = ei;
    const int* dst = ei + N_EDGES;

    float* xout  = (float*)d_out;           // [N]
    float* dense = xout + N_NODES;          // [N,1536] row-major

    // workspace carve-up (256B aligned)
    size_t off = 0;
    auto alloc = [&](size_t nbytes) -> void* {
        void* p = (char*)d_ws + off;
        off += (nbytes + 255) & ~(size_t)255;
        return p;
    };
    float* h    = (float*)alloc((size_t)N_NODES * HID * 4);   // GEMM out / pre-agg
    float* mean = (float*)alloc((size_t)N_NODES * HID * 4);   // SAGE mean
    float* hgat = (float*)alloc((size_t)N_NODES * NHEADS * 4);
    float* deg  = (float*)alloc((size_t)N_NODES * 4);
    float* dinv = (float*)alloc((size_t)N_NODES * 4);
    float* Wg   = (float*)alloc((size_t)DENSE_F * NHEADS * 4);
    float* asrc = (float*)alloc(32 * 4);
    float* adst = (float*)alloc(32 * 4);
    int*   cnt  = (int*)alloc((size_t)N_NODES * 4);
    int*   rowp = (int*)alloc((size_t)(N_NODES + 1) * 4);
    int*   woff = (int*)alloc((size_t)N_NODES * 4);
    int*   colx = (int*)alloc((size_t)N_EDGES * 4);
    float* wcsr = (float*)alloc((size_t)N_EDGES * 4);

    const int EB = (N_EDGES + 255) / 256;
    const int NB = (N_NODES + 255) / 256;

    // graph structure
    hipMemsetAsync(deg, 0, (size_t)N_NODES * 4, stream);
    hipMemsetAsync(cnt, 0, (size_t)N_NODES * 4, stream);
    build_stats<<<EB, 256, 0, stream>>>(dst, ew, deg, cnt);
    node_stats<<<NB, 256, 0, stream>>>(deg, dinv);
    scan_rowptr<<<1, 1024, 0, stream>>>(cnt, rowp, woff);
    scatter_csr<<<EB, 256, 0, stream>>>(src, dst, ew, woff, colx, wcsr);

    dim3 gblock(256);
    dim3 ggrid(HID / 64, (N_NODES + 63) / 64);

    // GCN1: h = x @ W1 ; x1 = relu(agg(h)+b1) -> dense cols [0,512)
    sgemm_nn<<<ggrid, gblock, 0, stream>>>(x, F_IN, W1, HID, h, HID, N_NODES, F_IN, 0);
    gcn_agg<<<N_NODES, 128, 0, stream>>>(h, rowp, colx, wcsr, dinv, deg, b1, dense, DENSE_F);

    // GCN2: h = x1 @ W2 ; x2 -> dense cols [512,1024)
    sgemm_nn<<<ggrid, gblock, 0, stream>>>(dense, DENSE_F, W2, HID, h, HID, N_NODES, HID, 0);
    gcn_agg<<<N_NODES, 128, 0, stream>>>(h, rowp, colx, wcsr, dinv, deg, b2, dense + HID, DENSE_F);

    // SAGE: mean of x1 neighbors; h = mean@Wl + x1@Wr ; x3 -> dense cols [1024,1536)
    sage_mean<<<N_NODES, 128, 0, stream>>>(dense, DENSE_F, rowp, colx, cnt, mean);
    sgemm_nn<<<ggrid, gblock, 0, stream>>>(mean, HID, sWl, HID, h, HID, N_NODES, HID, 0);
    sgemm_nn<<<ggrid, gblock, 0, stream>>>(dense, DENSE_F, sWr, HID, h, HID, N_NODES, HID, 1);
    sage_finish<<<(N_NODES * HID + 255) / 256, 256, 0, stream>>>(h, sb, dense + 2 * HID);

    // GAT (both convs fused into 20 head-columns)
    pack_gat<<<(DENSE_F * NHEADS + NHEADS + 255) / 256, 256, 0, stream>>>(
        g1W, g2W, g1as, g1ad, g2as, g2ad, Wg, asrc, adst);
    gat_linear<<<(N_NODES * NHEADS + 255) / 256, 256, 0, stream>>>(dense, Wg, hgat);
    gat_agg<<<N_NODES, 64, 0, stream>>>(hgat, rowp, colx, asrc, adst, g1b, g2b, xout);
}

// Round 2
// 1086.760 us; speedup vs baseline: 1.8423x; 1.8423x over previous
//
#include <hip/hip_runtime.h>
#include <hip/hip_bf16.h>
#include <stdint.h>

#define N_NODES 30000
#define M_PAD   30080      // 235 * 128, GEMM M padding
#define N_EDGES 480000
#define F_IN 376
#define K1   384           // F_IN padded to BK multiple
#define HID 512
#define DENSE_F 1536
#define NHEADS 20          // 4 (gat1) + 16 (gat2)
#define HG_LD 128          // hgat leading dim (GAT GEMM N padded to 128)

typedef __bf16 bf16_t;
typedef bf16_t bf16x8 __attribute__((ext_vector_type(8)));
typedef bf16_t bf16x4 __attribute__((ext_vector_type(4)));
typedef float  f32x4  __attribute__((ext_vector_type(4)));

// ---------------------------------------------------------------------------
// Stage 0: graph structure (CSR build), unchanged from R1
// ---------------------------------------------------------------------------
__global__ __launch_bounds__(256) void build_stats(
    const int* __restrict__ dst, const float* __restrict__ ew,
    float* __restrict__ deg, int* __restrict__ cnt)
{
    int e = blockIdx.x * 256 + threadIdx.x;
    if (e >= N_EDGES) return;
    int t = dst[e];
    atomicAdd(&deg[t], ew[e]);
    atomicAdd(&cnt[t], 1);
}

__global__ __launch_bounds__(256) void node_stats(
    float* __restrict__ deg, float* __restrict__ dinv)
{
    int i = blockIdx.x * 256 + threadIdx.x;
    if (i >= N_NODES) return;
    float d = deg[i] + 1.0f;
    deg[i] = d;
    dinv[i] = rsqrtf(d);
}

__global__ __launch_bounds__(1024) void scan_rowptr(
    const int* __restrict__ cnt, int* __restrict__ rowptr, int* __restrict__ woff)
{
    __shared__ int temp[1024];
    __shared__ int carry;
    int t = threadIdx.x;
    if (t == 0) carry = 0;
    __syncthreads();
    for (int base = 0; base < N_NODES; base += 1024) {
        int i = base + t;
        int v = (i < N_NODES) ? cnt[i] : 0;
        temp[t] = v;
        __syncthreads();
        for (int off = 1; off < 1024; off <<= 1) {
            int add = (t >= off) ? temp[t - off] : 0;
            __syncthreads();
            temp[t] += add;
            __syncthreads();
        }
        int excl = temp[t] - v;
        if (i < N_NODES) { rowptr[i] = carry + excl; woff[i] = carry + excl; }
        __syncthreads();
        if (t == 1023) carry += temp[1023];
        __syncthreads();
    }
    if (t == 0) rowptr[N_NODES] = carry;
}

__global__ __launch_bounds__(256) void scatter_csr(
    const int* __restrict__ src, const int* __restrict__ dst,
    const float* __restrict__ ew, int* __restrict__ woff,
    int* __restrict__ col, float* __restrict__ wcsr)
{
    int e = blockIdx.x * 256 + threadIdx.x;
    if (e >= N_EDGES) return;
    int t = dst[e];
    int p = atomicAdd(&woff[t], 1);
    col[p] = src[e];
    wcsr[p] = ew[e];
}

// ---------------------------------------------------------------------------
// x (fp32 [30000x376]) -> x_bf (bf16 [M_PAD x 384], zero-padded)
// ---------------------------------------------------------------------------
__global__ __launch_bounds__(256) void conv_x(
    const float* __restrict__ x, bf16_t* __restrict__ xb)
{
    int tid = blockIdx.x * 256 + threadIdx.x;
    if (tid >= M_PAD * K1) return;
    int r = tid / K1, c = tid - r * K1;
    float v = (r < N_NODES && c < F_IN) ? x[r * F_IN + c] : 0.f;
    xb[tid] = (bf16_t)v;
}

// ---------------------------------------------------------------------------
// Pack all weights into transposed bf16 (Bt[n][k], k contiguous):
//   W1t [512 x 384] (k>=376 zero), W2t [512 x 512],
//   Bst [512 x 1024] (k<512: Wl, else Wr), Wgt [128 x 1536] (n>=20 zero)
// plus asrc/adst head coefficient packs.
// ---------------------------------------------------------------------------
#define S1 (512 * K1)
#define S2 (512 * 512)
#define S3 (512 * 1024)
#define S4 (HG_LD * DENSE_F)
__global__ __launch_bounds__(256) void pack_weights(
    const float* __restrict__ W1, const float* __restrict__ W2,
    const float* __restrict__ Wl, const float* __restrict__ Wr,
    const float* __restrict__ g1W, const float* __restrict__ g2W,
    const float* __restrict__ a1s, const float* __restrict__ a1d,
    const float* __restrict__ a2s, const float* __restrict__ a2d,
    bf16_t* __restrict__ W1t, bf16_t* __restrict__ W2t,
    bf16_t* __restrict__ Bst, bf16_t* __restrict__ Wgt,
    float* __restrict__ asrc, float* __restrict__ adst)
{
    int tid = blockIdx.x * 256 + threadIdx.x;
    if (tid < S1) {
        int n = tid / K1, k = tid - n * K1;
        W1t[tid] = (bf16_t)((k < F_IN) ? W1[k * HID + n] : 0.f);
    } else if (tid < S1 + S2) {
        int t = tid - S1;
        int n = t >> 9, k = t & 511;
        W2t[t] = (bf16_t)W2[k * HID + n];
    } else if (tid < S1 + S2 + S3) {
        int t = tid - S1 - S2;
        int n = t >> 10, k = t & 1023;
        Bst[t] = (bf16_t)((k < HID) ? Wl[k * HID + n] : Wr[(k - HID) * HID + n]);
    } else if (tid < S1 + S2 + S3 + S4) {
        int t = tid - S1 - S2 - S3;
        int n = t / DENSE_F, k = t - n * DENSE_F;
        float v = (n < 4) ? g1W[k * 4 + n] : (n < NHEADS) ? g2W[k * 16 + (n - 4)] : 0.f;
        Wgt[t] = (bf16_t)v;
    } else if (tid < S1 + S2 + S3 + S4 + NHEADS) {
        int hh = tid - S1 - S2 - S3 - S4;
        asrc[hh] = (hh < 4) ? a1s[hh] : a2s[hh - 4];
        adst[hh] = (hh < 4) ? a1d[hh] : a2d[hh - 4];
    }
}

// ---------------------------------------------------------------------------
// bf16 MFMA GEMM (NT): C[M_PAD x N] = A[M_PAD x K] * Bt[N x K]^T, fp32 out.
// 128x128 tile, BK=32, 256 thr = 4 waves (2x2 of 64x64), 16x16x32 MFMA.
// A has two k-segments (A1 for k<ksplit, A2 after) to fuse SAGE's
// mean@Wl + x1@Wr into one K=1024 pass. LDS chunks XOR-swizzled so
// ds_read_b128 spreads banks; global_load_lds width=16 staging.
// ---------------------------------------------------------------------------
__global__ __launch_bounds__(256) void gemm_bf16(
    const bf16_t* __restrict__ A1, int lda1, int ksplit,
    const bf16_t* __restrict__ A2, int lda2,
    const bf16_t* __restrict__ Bt, int ldb,
    float* __restrict__ C, long ldc, int K)
{
    __shared__ bf16_t As[128 * 32];
    __shared__ bf16_t Bs[128 * 32];
    const int tid = threadIdx.x;
    const int wid = tid >> 6, lane = tid & 63;
    const int li = lane & 15, kq = lane >> 4;
    const int wm = (wid >> 1) * 64, wn = (wid & 1) * 64;
    const long r0 = (long)blockIdx.y * 128;
    const long n0 = (long)blockIdx.x * 128;

    f32x4 acc[4][4] = {};

    // staging: slot s (16B) holds row m=s>>2, k-chunk (s&3)^((m>>1)&3)
    const int s0 = wid * 64 + lane;
    const int s1 = 256 + s0;
    const int am0 = s0 >> 2, ak0 = (s0 & 3) ^ ((am0 >> 1) & 3);
    const int am1 = s1 >> 2, ak1 = (s1 & 3) ^ ((am1 >> 1) & 3);
    const int swz = (li >> 1) & 3;

    for (int k0 = 0; k0 < K; k0 += 32) {
        const bf16_t* Ab; int lda;
        if (k0 < ksplit) { Ab = A1 + k0;            lda = lda1; }
        else             { Ab = A2 + (k0 - ksplit); lda = lda2; }
        __builtin_amdgcn_global_load_lds(
            (const __attribute__((address_space(1))) void*)(Ab + (r0 + am0) * (long)lda + ak0 * 8),
            (__attribute__((address_space(3))) void*)(As + (wid * 64) * 8), 16, 0, 0);
        __builtin_amdgcn_global_load_lds(
            (const __attribute__((address_space(1))) void*)(Ab + (r0 + am1) * (long)lda + ak1 * 8),
            (__attribute__((address_space(3))) void*)(As + (256 + wid * 64) * 8), 16, 0, 0);
        __builtin_amdgcn_global_load_lds(
            (const __attribute__((address_space(1))) void*)(Bt + (n0 + am0) * (long)ldb + k0 + ak0 * 8),
            (__attribute__((address_space(3))) void*)(Bs + (wid * 64) * 8), 16, 0, 0);
        __builtin_amdgcn_global_load_lds(
            (const __attribute__((address_space(1))) void*)(Bt + (n0 + am1) * (long)ldb + k0 + ak1 * 8),
            (__attribute__((address_space(3))) void*)(Bs + (256 + wid * 64) * 8), 16, 0, 0);
        __syncthreads();   // drains vmcnt -> staging visible

        bf16x8 a[4], b[4];
#pragma unroll
        for (int f = 0; f < 4; ++f) {
            int m = wm + f * 16 + li;
            a[f] = *(const bf16x8*)(As + m * 32 + ((kq ^ swz) * 8));
            int n = wn + f * 16 + li;
            b[f] = *(const bf16x8*)(Bs + n * 32 + ((kq ^ swz) * 8));
        }
#pragma unroll
        for (int fm = 0; fm < 4; ++fm)
#pragma unroll
            for (int fn = 0; fn < 4; ++fn)
                acc[fm][fn] = __builtin_amdgcn_mfma_f32_16x16x32_bf16(
                    a[fm], b[fn], acc[fm][fn], 0, 0, 0);
        __syncthreads();   // protect LDS before next overwrite
    }

    // C/D layout: col = lane&15, row = (lane>>4)*4 + reg  [m89/m91-verified]
#pragma unroll
    for (int fm = 0; fm < 4; ++fm) {
#pragma unroll
        for (int r = 0; r < 4; ++r) {
            long row = r0 + wm + fm * 16 + kq * 4 + r;
            float* cp = C + row * ldc + n0 + wn + li;
#pragma unroll
            for (int fn = 0; fn < 4; ++fn)
                cp[fn * 16] = acc[fm][fn][r];
        }
    }
}

// ---------------------------------------------------------------------------
// GCN aggregation (fp32): out = relu(h[i]/deg + sum dinv[s]*w*dinv[i]*h[s] + b)
// writes fp32 into dense (d_out) and bf16 mirror into dense_bf
// ---------------------------------------------------------------------------
__global__ __launch_bounds__(128) void gcn_agg(
    const float* __restrict__ h, const int* __restrict__ rowptr,
    const int* __restrict__ col, const float* __restrict__ wcsr,
    const float* __restrict__ dinv, const float* __restrict__ deg,
    const float* __restrict__ bias, float* __restrict__ out,
    bf16_t* __restrict__ outb)
{
    int i = blockIdx.x;
    int c = threadIdx.x * 4;
    float4 acc = *reinterpret_cast<const float4*>(h + (long)i * HID + c);
    float selfw = 1.0f / deg[i];
    acc.x *= selfw; acc.y *= selfw; acc.z *= selfw; acc.w *= selfw;
    float di = dinv[i];
    int e0 = rowptr[i], e1 = rowptr[i + 1];
    for (int e = e0; e < e1; ++e) {
        int s = col[e];
        float nw = dinv[s] * wcsr[e] * di;
        float4 hv = *reinterpret_cast<const float4*>(h + (long)s * HID + c);
        acc.x = fmaf(nw, hv.x, acc.x);
        acc.y = fmaf(nw, hv.y, acc.y);
        acc.z = fmaf(nw, hv.z, acc.z);
        acc.w = fmaf(nw, hv.w, acc.w);
    }
    float4 b = *reinterpret_cast<const float4*>(bias + c);
    float4 o;
    o.x = fmaxf(acc.x + b.x, 0.f);
    o.y = fmaxf(acc.y + b.y, 0.f);
    o.z = fmaxf(acc.z + b.z, 0.f);
    o.w = fmaxf(acc.w + b.w, 0.f);
    *reinterpret_cast<float4*>(out + (long)i * DENSE_F + c) = o;
    bf16x4 ob = { (bf16_t)o.x, (bf16_t)o.y, (bf16_t)o.z, (bf16_t)o.w };
    *reinterpret_cast<bf16x4*>(outb + (long)i * DENSE_F + c) = ob;
}

// SAGE mean (fp32 read from dense, bf16 write)
__global__ __launch_bounds__(128) void sage_mean(
    const float* __restrict__ x1, const int* __restrict__ rowptr,
    const int* __restrict__ col, const int* __restrict__ cnt,
    bf16_t* __restrict__ meanb)
{
    int i = blockIdx.x;
    int c = threadIdx.x * 4;
    float4 acc = make_float4(0.f, 0.f, 0.f, 0.f);
    int e0 = rowptr[i], e1 = rowptr[i + 1];
    for (int e = e0; e < e1; ++e) {
        int s = col[e];
        float4 hv = *reinterpret_cast<const float4*>(x1 + (long)s * DENSE_F + c);
        acc.x += hv.x; acc.y += hv.y; acc.z += hv.z; acc.w += hv.w;
    }
    float inv = 1.0f / fmaxf((float)cnt[i], 1.0f);
    bf16x4 ob = { (bf16_t)(acc.x * inv), (bf16_t)(acc.y * inv),
                  (bf16_t)(acc.z * inv), (bf16_t)(acc.w * inv) };
    *reinterpret_cast<bf16x4*>(meanb + (long)i * HID + c) = ob;
}

// x3 = relu(h + sage_b) -> dense cols [1024,1536) fp32 + bf16 mirror
__global__ __launch_bounds__(256) void sage_finish(
    const float* __restrict__ h, const float* __restrict__ bias,
    float* __restrict__ out, bf16_t* __restrict__ outb)
{
    int tid = blockIdx.x * 256 + threadIdx.x;
    if (tid >= N_NODES * HID) return;
    int i = tid >> 9;
    int c = tid & (HID - 1);
    float v = fmaxf(h[tid] + bias[c], 0.f);
    out[(long)i * DENSE_F + c] = v;
    outb[(long)i * DENSE_F + c] = (bf16_t)v;
}

// per-dst GAT attention over CSR (+self loop), softmax shift-free
__global__ __launch_bounds__(64) void gat_agg(
    const float* __restrict__ hgat, const int* __restrict__ rowptr,
    const int* __restrict__ col, const float* __restrict__ asrc,
    const float* __restrict__ adst, const float* __restrict__ b1p,
    const float* __restrict__ b2p, float* __restrict__ xout)
{
    int i = blockIdx.x;
    int lane = threadIdx.x;
    int h = (lane < NHEADS) ? lane : 0;
    float hg_i = hgat[(long)i * HG_LD + h];
    float as = asrc[h], ad = adst[h];
    float adhg = ad * hg_i;
    float ev = hg_i * as + adhg;
    ev = ev > 0.f ? ev : 0.2f * ev;
    float ex = __expf(ev);
    float den = ex, og = ex * hg_i;
    int e0 = rowptr[i], e1 = rowptr[i + 1];
    for (int e = e0; e < e1; ++e) {
        int s = col[e];
        float hs = hgat[(long)s * HG_LD + h];
        float t = fmaf(hs, as, adhg);
        t = t > 0.f ? t : 0.2f * t;
        float x = __expf(t);
        den += x;
        og = fmaf(x, hs, og);
    }
    float out = (lane < NHEADS) ? og / den : 0.f;
    float s4 = out + __shfl_xor(out, 1);
    s4 += __shfl_xor(s4, 2);
    float g0 = __shfl(s4, 0);
    float g1 = __shfl(s4, 4);
    float g2 = __shfl(s4, 8);
    float g3 = __shfl(s4, 12);
    float g4 = __shfl(s4, 16);
    if (lane == 0) {
        float a1 = g0 * 0.25f + b1p[0];
        float a2 = (g1 + g2 + g3 + g4) * 0.0625f + b2p[0];
        xout[i] = 0.5f * (a1 + a2);
    }
}

// ---------------------------------------------------------------------------
extern "C" void kernel_launch(void* const* d_in, const int* in_sizes, int n_in,
                              void* d_out, int out_size, void* d_ws, size_t ws_size,
                              hipStream_t stream) {
    (void)in_sizes; (void)n_in; (void)out_size; (void)ws_size;
    const float* x    = (const float*)d_in[0];
    const int*   ei   = (const int*)d_in[1];
    const float* ew   = (const float*)d_in[2];
    const float* W1   = (const float*)d_in[3];
    const float* b1   = (const float*)d_in[4];
    const float* W2   = (const float*)d_in[5];
    const float* b2   = (const float*)d_in[6];
    const float* sWl  = (const float*)d_in[7];
    const float* sWr  = (const float*)d_in[8];
    const float* sb   = (const float*)d_in[9];
    const float* g1W  = (const float*)d_in[10];
    const float* g1as = (const float*)d_in[11];
    const float* g1ad = (const float*)d_in[12];
    const float* g1b  = (const float*)d_in[13];
    const float* g2W  = (const float*)d_in[14];
    const float* g2as = (const float*)d_in[15];
    const float* g2ad = (const float*)d_in[16];
    const float* g2b  = (const float*)d_in[17];

    const int* src = ei;
    const int* dst = ei + N_EDGES;

    float* xout  = (float*)d_out;          // [N]
    float* dense = xout + N_NODES;         // [N,1536] fp32 (output 2)

    size_t off = 0;
    auto alloc = [&](size_t nbytes) -> void* {
        void* p = (char*)d_ws + off;
        off += (nbytes + 255) & ~(size_t)255;
        return p;
    };
    float*  h        = (float*)alloc((size_t)M_PAD * HID * 4);      // GEMM out; reused as hgat
    bf16_t* dense_bf = (bf16_t*)alloc((size_t)M_PAD * DENSE_F * 2); // bf16 mirror of dense
    bf16_t* x_bf     = (bf16_t*)alloc((size_t)M_PAD * K1 * 2);
    bf16_t* mean_bf  = (bf16_t*)alloc((size_t)M_PAD * HID * 2);
    bf16_t* W1t      = (bf16_t*)alloc((size_t)512 * K1 * 2);
    bf16_t* W2t      = (bf16_t*)alloc((size_t)512 * 512 * 2);
    bf16_t* Bst      = (bf16_t*)alloc((size_t)512 * 1024 * 2);
    bf16_t* Wgt      = (bf16_t*)alloc((size_t)HG_LD * DENSE_F * 2);
    float*  deg      = (float*)alloc((size_t)N_NODES * 4);
    float*  dinv     = (float*)alloc((size_t)N_NODES * 4);
    float*  asrc     = (float*)alloc(32 * 4);
    float*  adst     = (float*)alloc(32 * 4);
    int*    cnt      = (int*)alloc((size_t)N_NODES * 4);
    int*    rowp     = (int*)alloc((size_t)(N_NODES + 1) * 4);
    int*    woff     = (int*)alloc((size_t)N_NODES * 4);
    int*    colx     = (int*)alloc((size_t)N_EDGES * 4);
    float*  wcsr     = (float*)alloc((size_t)N_EDGES * 4);
    float*  hgat     = h;   // alias: h free by the time GAT GEMM runs

    const int EB = (N_EDGES + 255) / 256;
    const int NB = (N_NODES + 255) / 256;

    // graph structure
    hipMemsetAsync(deg, 0, (size_t)N_NODES * 4, stream);
    hipMemsetAsync(cnt, 0, (size_t)N_NODES * 4, stream);
    build_stats<<<EB, 256, 0, stream>>>(dst, ew, deg, cnt);
    node_stats<<<NB, 256, 0, stream>>>(deg, dinv);
    scan_rowptr<<<1, 1024, 0, stream>>>(cnt, rowp, woff);
    scatter_csr<<<EB, 256, 0, stream>>>(src, dst, ew, woff, colx, wcsr);

    // operand conversion / packing (overlaps CSR build on the stream queue)
    conv_x<<<(M_PAD * K1 + 255) / 256, 256, 0, stream>>>(x, x_bf);
    pack_weights<<<(S1 + S2 + S3 + S4 + NHEADS + 255) / 256, 256, 0, stream>>>(
        W1, W2, sWl, sWr, g1W, g2W, g1as, g1ad, g2as, g2ad,
        W1t, W2t, Bst, Wgt, asrc, adst);

    const dim3 gB(256);
    const dim3 g512(HID / 128, M_PAD / 128);   // (4, 235)
    const dim3 g128(1, M_PAD / 128);           // (1, 235)

    // GCN1: h = x @ W1 ; x1 -> dense[:,0:512]
    gemm_bf16<<<g512, gB, 0, stream>>>(x_bf, K1, K1, x_bf, K1, W1t, K1, h, HID, K1);
    gcn_agg<<<N_NODES, 128, 0, stream>>>(h, rowp, colx, wcsr, dinv, deg, b1,
                                         dense, dense_bf);
    // GCN2: h = x1 @ W2 ; x2 -> dense[:,512:1024]
    gemm_bf16<<<g512, gB, 0, stream>>>(dense_bf, DENSE_F, HID, dense_bf, DENSE_F,
                                       W2t, HID, h, HID, HID);
    gcn_agg<<<N_NODES, 128, 0, stream>>>(h, rowp, colx, wcsr, dinv, deg, b2,
                                         dense + HID, dense_bf + HID);
    // SAGE: mean of x1 ; h = [mean|x1] @ [Wl;Wr] ; x3 -> dense[:,1024:1536]
    sage_mean<<<N_NODES, 128, 0, stream>>>(dense, rowp, colx, cnt, mean_bf);
    gemm_bf16<<<g512, gB, 0, stream>>>(mean_bf, HID, HID, dense_bf, DENSE_F,
                                       Bst, 1024, h, HID, 1024);
    sage_finish<<<(N_NODES * HID + 255) / 256, 256, 0, stream>>>(
        h, sb, dense + 2 * HID, dense_bf + 2 * HID);

    // GAT: hgat = dense @ Wg (N padded to 128), then CSR softmax-aggregate
    gemm_bf16<<<g128, gB, 0, stream>>>(dense_bf, DENSE_F, DENSE_F, dense_bf, DENSE_F,
                                       Wgt, DENSE_F, hgat, HG_LD, DENSE_F);
    gat_agg<<<N_NODES, 64, 0, stream>>>(hgat, rowp, colx, asrc, adst, g1b, g2b, xout);
}

// Round 3
// 871.155 us; speedup vs baseline: 2.2982x; 1.2475x over previous
//
#include <hip/hip_runtime.h>
#include <hip/hip_bf16.h>
#include <stdint.h>

#define N_NODES 30000
#define M_PAD   30080      // 235 * 128, GEMM M padding
#define N_EDGES 480000
#define F_IN 376
#define K1   384           // F_IN padded to BK multiple
#define HID 512
#define DENSE_F 1536
#define NHEADS 20          // 4 (gat1) + 16 (gat2)
#define HG_LD 128          // hgat leading dim (GAT GEMM N padded to 128)

typedef __bf16 bf16_t;
typedef bf16_t bf16x8 __attribute__((ext_vector_type(8)));
typedef bf16_t bf16x4 __attribute__((ext_vector_type(4)));
typedef float  f32x4  __attribute__((ext_vector_type(4)));

// ---------------------------------------------------------------------------
// Stage 0: graph structure (CSR build)
// ---------------------------------------------------------------------------
__global__ __launch_bounds__(256) void build_stats(
    const int* __restrict__ dst, const float* __restrict__ ew,
    float* __restrict__ deg, int* __restrict__ cnt)
{
    int e = blockIdx.x * 256 + threadIdx.x;
    if (e >= N_EDGES) return;
    int t = dst[e];
    atomicAdd(&deg[t], ew[e]);
    atomicAdd(&cnt[t], 1);
}

__global__ __launch_bounds__(256) void node_stats(
    float* __restrict__ deg, float* __restrict__ dinv)
{
    int i = blockIdx.x * 256 + threadIdx.x;
    if (i >= N_NODES) return;
    float d = deg[i] + 1.0f;
    deg[i] = d;
    dinv[i] = rsqrtf(d);
}

__global__ __launch_bounds__(1024) void scan_rowptr(
    const int* __restrict__ cnt, int* __restrict__ rowptr, int* __restrict__ woff)
{
    __shared__ int temp[1024];
    __shared__ int carry;
    int t = threadIdx.x;
    if (t == 0) carry = 0;
    __syncthreads();
    for (int base = 0; base < N_NODES; base += 1024) {
        int i = base + t;
        int v = (i < N_NODES) ? cnt[i] : 0;
        temp[t] = v;
        __syncthreads();
        for (int off = 1; off < 1024; off <<= 1) {
            int add = (t >= off) ? temp[t - off] : 0;
            __syncthreads();
            temp[t] += add;
            __syncthreads();
        }
        int excl = temp[t] - v;
        if (i < N_NODES) { rowptr[i] = carry + excl; woff[i] = carry + excl; }
        __syncthreads();
        if (t == 1023) carry += temp[1023];
        __syncthreads();
    }
    if (t == 0) rowptr[N_NODES] = carry;
}

__global__ __launch_bounds__(256) void scatter_csr(
    const int* __restrict__ src, const int* __restrict__ dst,
    const float* __restrict__ ew, int* __restrict__ woff,
    int* __restrict__ col, float* __restrict__ wcsr)
{
    int e = blockIdx.x * 256 + threadIdx.x;
    if (e >= N_EDGES) return;
    int t = dst[e];
    int p = atomicAdd(&woff[t], 1);
    col[p] = src[e];
    wcsr[p] = ew[e];
}

// ---------------------------------------------------------------------------
// x (fp32 [30000x376]) -> x_bf (bf16 [M_PAD x 384], zero-padded)
// ---------------------------------------------------------------------------
__global__ __launch_bounds__(256) void conv_x(
    const float* __restrict__ x, bf16_t* __restrict__ xb)
{
    int tid = blockIdx.x * 256 + threadIdx.x;
    if (tid >= M_PAD * K1) return;
    int r = tid / K1, c = tid - r * K1;
    float v = (r < N_NODES && c < F_IN) ? x[r * F_IN + c] : 0.f;
    xb[tid] = (bf16_t)v;
}

// ---------------------------------------------------------------------------
// Pack weights transposed bf16 (Bt[n][k], k contiguous)
// ---------------------------------------------------------------------------
#define S1 (512 * K1)
#define S2 (512 * 512)
#define S3 (512 * 1024)
#define S4 (HG_LD * DENSE_F)
__global__ __launch_bounds__(256) void pack_weights(
    const float* __restrict__ W1, const float* __restrict__ W2,
    const float* __restrict__ Wl, const float* __restrict__ Wr,
    const float* __restrict__ g1W, const float* __restrict__ g2W,
    const float* __restrict__ a1s, const float* __restrict__ a1d,
    const float* __restrict__ a2s, const float* __restrict__ a2d,
    bf16_t* __restrict__ W1t, bf16_t* __restrict__ W2t,
    bf16_t* __restrict__ Bst, bf16_t* __restrict__ Wgt,
    float* __restrict__ asrc, float* __restrict__ adst)
{
    int tid = blockIdx.x * 256 + threadIdx.x;
    if (tid < S1) {
        int n = tid / K1, k = tid - n * K1;
        W1t[tid] = (bf16_t)((k < F_IN) ? W1[k * HID + n] : 0.f);
    } else if (tid < S1 + S2) {
        int t = tid - S1;
        int n = t >> 9, k = t & 511;
        W2t[t] = (bf16_t)W2[k * HID + n];
    } else if (tid < S1 + S2 + S3) {
        int t = tid - S1 - S2;
        int n = t >> 10, k = t & 1023;
        Bst[t] = (bf16_t)((k < HID) ? Wl[k * HID + n] : Wr[(k - HID) * HID + n]);
    } else if (tid < S1 + S2 + S3 + S4) {
        int t = tid - S1 - S2 - S3;
        int n = t / DENSE_F, k = t - n * DENSE_F;
        float v = (n < 4) ? g1W[k * 4 + n] : (n < NHEADS) ? g2W[k * 16 + (n - 4)] : 0.f;
        Wgt[t] = (bf16_t)v;
    } else if (tid < S1 + S2 + S3 + S4 + NHEADS) {
        int hh = tid - S1 - S2 - S3 - S4;
        asrc[hh] = (hh < 4) ? a1s[hh] : a2s[hh - 4];
        adst[hh] = (hh < 4) ? a1d[hh] : a2d[hh - 4];
    }
}

// ---------------------------------------------------------------------------
// bf16 MFMA GEMM (NT): C = A * Bt^T, fp32 acc; output fp32 (C) or bf16 (Cb).
// 128x128 tile, BK=32, 4 waves, 16x16x32 MFMA, global_load_lds staging.
// A has two k-segments (ksplit) to fuse SAGE's mean@Wl + x1@Wr.
// ---------------------------------------------------------------------------
__global__ __launch_bounds__(256) void gemm_bf16(
    const bf16_t* __restrict__ A1, int lda1, int ksplit,
    const bf16_t* __restrict__ A2, int lda2,
    const bf16_t* __restrict__ Bt, int ldb,
    float* __restrict__ C, bf16_t* __restrict__ Cb, long ldc, int K)
{
    __shared__ bf16_t As[128 * 32];
    __shared__ bf16_t Bs[128 * 32];
    const int tid = threadIdx.x;
    const int wid = tid >> 6, lane = tid & 63;
    const int li = lane & 15, kq = lane >> 4;
    const int wm = (wid >> 1) * 64, wn = (wid & 1) * 64;
    const long r0 = (long)blockIdx.y * 128;
    const long n0 = (long)blockIdx.x * 128;

    f32x4 acc[4][4] = {};

    const int s0 = wid * 64 + lane;
    const int s1 = 256 + s0;
    const int am0 = s0 >> 2, ak0 = (s0 & 3) ^ ((am0 >> 1) & 3);
    const int am1 = s1 >> 2, ak1 = (s1 & 3) ^ ((am1 >> 1) & 3);
    const int swz = (li >> 1) & 3;

    for (int k0 = 0; k0 < K; k0 += 32) {
        const bf16_t* Ab; int lda;
        if (k0 < ksplit) { Ab = A1 + k0;            lda = lda1; }
        else             { Ab = A2 + (k0 - ksplit); lda = lda2; }
        __builtin_amdgcn_global_load_lds(
            (const __attribute__((address_space(1))) void*)(Ab + (r0 + am0) * (long)lda + ak0 * 8),
            (__attribute__((address_space(3))) void*)(As + (wid * 64) * 8), 16, 0, 0);
        __builtin_amdgcn_global_load_lds(
            (const __attribute__((address_space(1))) void*)(Ab + (r0 + am1) * (long)lda + ak1 * 8),
            (__attribute__((address_space(3))) void*)(As + (256 + wid * 64) * 8), 16, 0, 0);
        __builtin_amdgcn_global_load_lds(
            (const __attribute__((address_space(1))) void*)(Bt + (n0 + am0) * (long)ldb + k0 + ak0 * 8),
            (__attribute__((address_space(3))) void*)(Bs + (wid * 64) * 8), 16, 0, 0);
        __builtin_amdgcn_global_load_lds(
            (const __attribute__((address_space(1))) void*)(Bt + (n0 + am1) * (long)ldb + k0 + ak1 * 8),
            (__attribute__((address_space(3))) void*)(Bs + (256 + wid * 64) * 8), 16, 0, 0);
        __syncthreads();

        bf16x8 a[4], b[4];
#pragma unroll
        for (int f = 0; f < 4; ++f) {
            int m = wm + f * 16 + li;
            a[f] = *(const bf16x8*)(As + m * 32 + ((kq ^ swz) * 8));
            int n = wn + f * 16 + li;
            b[f] = *(const bf16x8*)(Bs + n * 32 + ((kq ^ swz) * 8));
        }
#pragma unroll
        for (int fm = 0; fm < 4; ++fm)
#pragma unroll
            for (int fn = 0; fn < 4; ++fn)
                acc[fm][fn] = __builtin_amdgcn_mfma_f32_16x16x32_bf16(
                    a[fm], b[fn], acc[fm][fn], 0, 0, 0);
        __syncthreads();
    }

    // C/D layout: col = lane&15, row = (lane>>4)*4 + reg
    if (Cb) {
#pragma unroll
        for (int fm = 0; fm < 4; ++fm)
#pragma unroll
            for (int r = 0; r < 4; ++r) {
                long row = r0 + wm + fm * 16 + kq * 4 + r;
                bf16_t* cp = Cb + row * ldc + n0 + wn + li;
#pragma unroll
                for (int fn = 0; fn < 4; ++fn)
                    cp[fn * 16] = (bf16_t)acc[fm][fn][r];
            }
    } else {
#pragma unroll
        for (int fm = 0; fm < 4; ++fm)
#pragma unroll
            for (int r = 0; r < 4; ++r) {
                long row = r0 + wm + fm * 16 + kq * 4 + r;
                float* cp = C + row * ldc + n0 + wn + li;
#pragma unroll
                for (int fn = 0; fn < 4; ++fn)
                    cp[fn * 16] = acc[fm][fn][r];
            }
    }
}

// ---------------------------------------------------------------------------
// GCN aggregation: one wave per dst node; lane owns 8 cols (bf16x8 = 16B).
// h is bf16 [N x 512]. Two independent accumulator chains for MLP.
// ---------------------------------------------------------------------------
__global__ __launch_bounds__(64) void gcn_agg(
    const bf16_t* __restrict__ hb, const int* __restrict__ rowptr,
    const int* __restrict__ col, const float* __restrict__ wcsr,
    const float* __restrict__ dinv, const float* __restrict__ deg,
    const float* __restrict__ bias, float* __restrict__ out,
    bf16_t* __restrict__ outb)
{
    int i = blockIdx.x;
    int c = threadIdx.x * 8;
    float di = dinv[i];
    float selfw = 1.0f / deg[i];
    bf16x8 sv = *(const bf16x8*)(hb + (long)i * HID + c);
    float acc0[8], acc1[8];
#pragma unroll
    for (int j = 0; j < 8; ++j) { acc0[j] = selfw * (float)sv[j]; acc1[j] = 0.f; }
    int e = rowptr[i], e1 = rowptr[i + 1];
    for (; e + 1 < e1; e += 2) {
        int sA = col[e], sB = col[e + 1];
        float wA = dinv[sA] * wcsr[e] * di;
        float wB = dinv[sB] * wcsr[e + 1] * di;
        bf16x8 vA = *(const bf16x8*)(hb + (long)sA * HID + c);
        bf16x8 vB = *(const bf16x8*)(hb + (long)sB * HID + c);
#pragma unroll
        for (int j = 0; j < 8; ++j) {
            acc0[j] = fmaf(wA, (float)vA[j], acc0[j]);
            acc1[j] = fmaf(wB, (float)vB[j], acc1[j]);
        }
    }
    if (e < e1) {
        int sA = col[e];
        float wA = dinv[sA] * wcsr[e] * di;
        bf16x8 vA = *(const bf16x8*)(hb + (long)sA * HID + c);
#pragma unroll
        for (int j = 0; j < 8; ++j) acc0[j] = fmaf(wA, (float)vA[j], acc0[j]);
    }
    float o[8];
#pragma unroll
    for (int j = 0; j < 8; ++j)
        o[j] = fmaxf(acc0[j] + acc1[j] + bias[c + j], 0.f);
    float* op = out + (long)i * DENSE_F + c;
    *reinterpret_cast<float4*>(op)     = make_float4(o[0], o[1], o[2], o[3]);
    *reinterpret_cast<float4*>(op + 4) = make_float4(o[4], o[5], o[6], o[7]);
    bf16x8 ob;
#pragma unroll
    for (int j = 0; j < 8; ++j) ob[j] = (bf16_t)o[j];
    *reinterpret_cast<bf16x8*>(outb + (long)i * DENSE_F + c) = ob;
}

// SAGE mean: one wave per node, gathers bf16 x1 rows from dense_bf
__global__ __launch_bounds__(64) void sage_mean(
    const bf16_t* __restrict__ x1b, const int* __restrict__ rowptr,
    const int* __restrict__ col, const int* __restrict__ cnt,
    bf16_t* __restrict__ meanb)
{
    int i = blockIdx.x;
    int c = threadIdx.x * 8;
    float acc0[8] = {}, acc1[8] = {};
    int e = rowptr[i], e1 = rowptr[i + 1];
    for (; e + 1 < e1; e += 2) {
        int sA = col[e], sB = col[e + 1];
        bf16x8 vA = *(const bf16x8*)(x1b + (long)sA * DENSE_F + c);
        bf16x8 vB = *(const bf16x8*)(x1b + (long)sB * DENSE_F + c);
#pragma unroll
        for (int j = 0; j < 8; ++j) {
            acc0[j] += (float)vA[j];
            acc1[j] += (float)vB[j];
        }
    }
    if (e < e1) {
        int sA = col[e];
        bf16x8 vA = *(const bf16x8*)(x1b + (long)sA * DENSE_F + c);
#pragma unroll
        for (int j = 0; j < 8; ++j) acc0[j] += (float)vA[j];
    }
    float inv = 1.0f / fmaxf((float)cnt[i], 1.0f);
    bf16x8 ob;
#pragma unroll
    for (int j = 0; j < 8; ++j) ob[j] = (bf16_t)((acc0[j] + acc1[j]) * inv);
    *reinterpret_cast<bf16x8*>(meanb + (long)i * HID + c) = ob;
}

// x3 = relu(h + sage_b) -> dense cols [1024,1536) fp32 + bf16 mirror
__global__ __launch_bounds__(256) void sage_finish(
    const float* __restrict__ h, const float* __restrict__ bias,
    float* __restrict__ out, bf16_t* __restrict__ outb)
{
    int tid = blockIdx.x * 256 + threadIdx.x;
    if (tid >= N_NODES * HID) return;
    int i = tid >> 9;
    int c = tid & (HID - 1);
    float v = fmaxf(h[tid] + bias[c], 0.f);
    out[(long)i * DENSE_F + c] = v;
    outb[(long)i * DENSE_F + c] = (bf16_t)v;
}

// per-dst GAT attention over CSR (+self loop), softmax shift-free
__global__ __launch_bounds__(64) void gat_agg(
    const float* __restrict__ hgat, const int* __restrict__ rowptr,
    const int* __restrict__ col, const float* __restrict__ asrc,
    const float* __restrict__ adst, const float* __restrict__ b1p,
    const float* __restrict__ b2p, float* __restrict__ xout)
{
    int i = blockIdx.x;
    int lane = threadIdx.x;
    int h = (lane < NHEADS) ? lane : 0;
    float hg_i = hgat[(long)i * HG_LD + h];
    float as = asrc[h], ad = adst[h];
    float adhg = ad * hg_i;
    float ev = hg_i * as + adhg;
    ev = ev > 0.f ? ev : 0.2f * ev;
    float ex = __expf(ev);
    float den = ex, og = ex * hg_i;
    int e0 = rowptr[i], e1 = rowptr[i + 1];
    for (int e = e0; e < e1; ++e) {
        int s = col[e];
        float hs = hgat[(long)s * HG_LD + h];
        float t = fmaf(hs, as, adhg);
        t = t > 0.f ? t : 0.2f * t;
        float x = __expf(t);
        den += x;
        og = fmaf(x, hs, og);
    }
    float out = (lane < NHEADS) ? og / den : 0.f;
    float s4 = out + __shfl_xor(out, 1);
    s4 += __shfl_xor(s4, 2);
    float g0 = __shfl(s4, 0);
    float g1 = __shfl(s4, 4);
    float g2 = __shfl(s4, 8);
    float g3 = __shfl(s4, 12);
    float g4 = __shfl(s4, 16);
    if (lane == 0) {
        float a1 = g0 * 0.25f + b1p[0];
        float a2 = (g1 + g2 + g3 + g4) * 0.0625f + b2p[0];
        xout[i] = 0.5f * (a1 + a2);
    }
}

// ---------------------------------------------------------------------------
extern "C" void kernel_launch(void* const* d_in, const int* in_sizes, int n_in,
                              void* d_out, int out_size, void* d_ws, size_t ws_size,
                              hipStream_t stream) {
    (void)in_sizes; (void)n_in; (void)out_size; (void)ws_size;
    const float* x    = (const float*)d_in[0];
    const int*   ei   = (const int*)d_in[1];
    const float* ew   = (const float*)d_in[2];
    const float* W1   = (const float*)d_in[3];
    const float* b1   = (const float*)d_in[4];
    const float* W2   = (const float*)d_in[5];
    const float* b2   = (const float*)d_in[6];
    const float* sWl  = (const float*)d_in[7];
    const float* sWr  = (const float*)d_in[8];
    const float* sb   = (const float*)d_in[9];
    const float* g1W  = (const float*)d_in[10];
    const float* g1as = (const float*)d_in[11];
    const float* g1ad = (const float*)d_in[12];
    const float* g1b  = (const float*)d_in[13];
    const float* g2W  = (const float*)d_in[14];
    const float* g2as = (const float*)d_in[15];
    const float* g2ad = (const float*)d_in[16];
    const float* g2b  = (const float*)d_in[17];

    const int* src = ei;
    const int* dst = ei + N_EDGES;

    float* xout  = (float*)d_out;          // [N]
    float* dense = xout + N_NODES;         // [N,1536] fp32 (output 2)

    size_t off = 0;
    auto alloc = [&](size_t nbytes) -> void* {
        void* p = (char*)d_ws + off;
        off += (nbytes + 255) & ~(size_t)255;
        return p;
    };
    float*  h        = (float*)alloc((size_t)M_PAD * HID * 4);      // fp32 (SAGE/GAT)
    bf16_t* h_bf     = (bf16_t*)h;   // alias: GCN phases use bf16, disjoint in time
    bf16_t* dense_bf = (bf16_t*)alloc((size_t)M_PAD * DENSE_F * 2);
    bf16_t* x_bf     = (bf16_t*)alloc((size_t)M_PAD * K1 * 2);
    bf16_t* mean_bf  = (bf16_t*)alloc((size_t)M_PAD * HID * 2);
    bf16_t* W1t      = (bf16_t*)alloc((size_t)512 * K1 * 2);
    bf16_t* W2t      = (bf16_t*)alloc((size_t)512 * 512 * 2);
    bf16_t* Bst      = (bf16_t*)alloc((size_t)512 * 1024 * 2);
    bf16_t* Wgt      = (bf16_t*)alloc((size_t)HG_LD * DENSE_F * 2);
    float*  deg      = (float*)alloc((size_t)N_NODES * 4);
    float*  dinv     = (float*)alloc((size_t)N_NODES * 4);
    float*  asrc     = (float*)alloc(32 * 4);
    float*  adst     = (float*)alloc(32 * 4);
    int*    cnt      = (int*)alloc((size_t)N_NODES * 4);
    int*    rowp     = (int*)alloc((size_t)(N_NODES + 1) * 4);
    int*    woff     = (int*)alloc((size_t)N_NODES * 4);
    int*    colx     = (int*)alloc((size_t)N_EDGES * 4);
    float*  wcsr     = (float*)alloc((size_t)N_EDGES * 4);
    float*  hgat     = h;   // alias: h free again by the GAT GEMM

    const int EB = (N_EDGES + 255) / 256;
    const int NB = (N_NODES + 255) / 256;

    hipMemsetAsync(deg, 0, (size_t)N_NODES * 4, stream);
    hipMemsetAsync(cnt, 0, (size_t)N_NODES * 4, stream);
    build_stats<<<EB, 256, 0, stream>>>(dst, ew, deg, cnt);
    node_stats<<<NB, 256, 0, stream>>>(deg, dinv);
    scan_rowptr<<<1, 1024, 0, stream>>>(cnt, rowp, woff);
    scatter_csr<<<EB, 256, 0, stream>>>(src, dst, ew, woff, colx, wcsr);

    conv_x<<<(M_PAD * K1 + 255) / 256, 256, 0, stream>>>(x, x_bf);
    pack_weights<<<(S1 + S2 + S3 + S4 + NHEADS + 255) / 256, 256, 0, stream>>>(
        W1, W2, sWl, sWr, g1W, g2W, g1as, g1ad, g2as, g2ad,
        W1t, W2t, Bst, Wgt, asrc, adst);

    const dim3 gB(256);
    const dim3 g512(HID / 128, M_PAD / 128);   // (4, 235)
    const dim3 g128(1, M_PAD / 128);           // (1, 235)

    // GCN1: h_bf = x @ W1 (bf16 out) ; x1 -> dense[:,0:512]
    gemm_bf16<<<g512, gB, 0, stream>>>(x_bf, K1, K1, x_bf, K1, W1t, K1,
                                       nullptr, h_bf, HID, K1);
    gcn_agg<<<N_NODES, 64, 0, stream>>>(h_bf, rowp, colx, wcsr, dinv, deg, b1,
                                        dense, dense_bf);
    // GCN2: h_bf = x1 @ W2 ; x2 -> dense[:,512:1024]
    gemm_bf16<<<g512, gB, 0, stream>>>(dense_bf, DENSE_F, HID, dense_bf, DENSE_F,
                                       W2t, HID, nullptr, h_bf, HID, HID);
    gcn_agg<<<N_NODES, 64, 0, stream>>>(h_bf, rowp, colx, wcsr, dinv, deg, b2,
                                        dense + HID, dense_bf + HID);
    // SAGE: mean of x1 (bf16 gather) ; h = [mean|x1] @ [Wl;Wr] (fp32 out)
    sage_mean<<<N_NODES, 64, 0, stream>>>(dense_bf, rowp, colx, cnt, mean_bf);
    gemm_bf16<<<g512, gB, 0, stream>>>(mean_bf, HID, HID, dense_bf, DENSE_F,
                                       Bst, 1024, h, nullptr, HID, 1024);
    sage_finish<<<(N_NODES * HID + 255) / 256, 256, 0, stream>>>(
        h, sb, dense + 2 * HID, dense_bf + 2 * HID);

    // GAT: hgat = dense @ Wg (fp32 out, N padded to 128), then CSR aggregate
    gemm_bf16<<<g128, gB, 0, stream>>>(dense_bf, DENSE_F, DENSE_F, dense_bf, DENSE_F,
                                       Wgt, DENSE_F, hgat, nullptr, HG_LD, DENSE_F);
    gat_agg<<<N_NODES, 64, 0, stream>>>(hgat, rowp, colx, asrc, adst, g1b, g2b, xout);
}

// Round 4
// 802.821 us; speedup vs baseline: 2.4939x; 1.0851x over previous
//
#include <hip/hip_runtime.h>
#include <hip/hip_bf16.h>
#include <stdint.h>

#define N_NODES 30000
#define M_PAD   30080      // 235 * 128, GEMM M padding
#define N_EDGES 480000
#define F_IN 376
#define K1   384           // F_IN padded to BK multiple
#define HID 512
#define DENSE_F 1536
#define NHEADS 20          // 4 (gat1) + 16 (gat2)
#define HG_LD 32           // hgat leading dim (fp32): 3.85 MB, L2-resident

typedef __bf16 bf16_t;
typedef bf16_t bf16x8 __attribute__((ext_vector_type(8)));
typedef float  f32x4  __attribute__((ext_vector_type(4)));

// ---------------------------------------------------------------------------
// Stage 0: graph structure (CSR build)
// ---------------------------------------------------------------------------
__global__ __launch_bounds__(256) void build_stats(
    const int* __restrict__ dst, const float* __restrict__ ew,
    float* __restrict__ deg, int* __restrict__ cnt)
{
    int e = blockIdx.x * 256 + threadIdx.x;
    if (e >= N_EDGES) return;
    int t = dst[e];
    atomicAdd(&deg[t], ew[e]);
    atomicAdd(&cnt[t], 1);
}

__global__ __launch_bounds__(256) void node_stats(
    float* __restrict__ deg, float* __restrict__ dinv)
{
    int i = blockIdx.x * 256 + threadIdx.x;
    if (i >= N_NODES) return;
    float d = deg[i] + 1.0f;
    deg[i] = d;
    dinv[i] = rsqrtf(d);
}

__global__ __launch_bounds__(1024) void scan_rowptr(
    const int* __restrict__ cnt, int* __restrict__ rowptr, int* __restrict__ woff)
{
    __shared__ int temp[1024];
    __shared__ int carry;
    int t = threadIdx.x;
    if (t == 0) carry = 0;
    __syncthreads();
    for (int base = 0; base < N_NODES; base += 1024) {
        int i = base + t;
        int v = (i < N_NODES) ? cnt[i] : 0;
        temp[t] = v;
        __syncthreads();
        for (int off = 1; off < 1024; off <<= 1) {
            int add = (t >= off) ? temp[t - off] : 0;
            __syncthreads();
            temp[t] += add;
            __syncthreads();
        }
        int excl = temp[t] - v;
        if (i < N_NODES) { rowptr[i] = carry + excl; woff[i] = carry + excl; }
        __syncthreads();
        if (t == 1023) carry += temp[1023];
        __syncthreads();
    }
    if (t == 0) rowptr[N_NODES] = carry;
}

__global__ __launch_bounds__(256) void scatter_csr(
    const int* __restrict__ src, const int* __restrict__ dst,
    const float* __restrict__ ew, int* __restrict__ woff,
    int* __restrict__ col, float* __restrict__ wcsr)
{
    int e = blockIdx.x * 256 + threadIdx.x;
    if (e >= N_EDGES) return;
    int t = dst[e];
    int p = atomicAdd(&woff[t], 1);
    col[p] = src[e];
    wcsr[p] = ew[e];
}

// ---------------------------------------------------------------------------
// x (fp32 [30000x376]) -> x_bf (bf16 [M_PAD x 384], zero-padded)
// ---------------------------------------------------------------------------
__global__ __launch_bounds__(256) void conv_x(
    const float* __restrict__ x, bf16_t* __restrict__ xb)
{
    int tid = blockIdx.x * 256 + threadIdx.x;
    if (tid >= M_PAD * K1) return;
    int r = tid / K1, c = tid - r * K1;
    float v = (r < N_NODES && c < F_IN) ? x[r * F_IN + c] : 0.f;
    xb[tid] = (bf16_t)v;
}

// ---------------------------------------------------------------------------
// Pack weights transposed bf16 (Bt[n][k], k contiguous)
// ---------------------------------------------------------------------------
#define S1 (512 * K1)
#define S2 (512 * 512)
#define S3 (512 * 1024)
#define S4 (128 * DENSE_F)
__global__ __launch_bounds__(256) void pack_weights(
    const float* __restrict__ W1, const float* __restrict__ W2,
    const float* __restrict__ Wl, const float* __restrict__ Wr,
    const float* __restrict__ g1W, const float* __restrict__ g2W,
    const float* __restrict__ a1s, const float* __restrict__ a1d,
    const float* __restrict__ a2s, const float* __restrict__ a2d,
    bf16_t* __restrict__ W1t, bf16_t* __restrict__ W2t,
    bf16_t* __restrict__ Bst, bf16_t* __restrict__ Wgt,
    float* __restrict__ asrc, float* __restrict__ adst)
{
    int tid = blockIdx.x * 256 + threadIdx.x;
    if (tid < S1) {
        int n = tid / K1, k = tid - n * K1;
        W1t[tid] = (bf16_t)((k < F_IN) ? W1[k * HID + n] : 0.f);
    } else if (tid < S1 + S2) {
        int t = tid - S1;
        int n = t >> 9, k = t & 511;
        W2t[t] = (bf16_t)W2[k * HID + n];
    } else if (tid < S1 + S2 + S3) {
        int t = tid - S1 - S2;
        int n = t >> 10, k = t & 1023;
        Bst[t] = (bf16_t)((k < HID) ? Wl[k * HID + n] : Wr[(k - HID) * HID + n]);
    } else if (tid < S1 + S2 + S3 + S4) {
        int t = tid - S1 - S2 - S3;
        int n = t / DENSE_F, k = t - n * DENSE_F;
        float v = (n < 4) ? g1W[k * 4 + n] : (n < NHEADS) ? g2W[k * 16 + (n - 4)] : 0.f;
        Wgt[t] = (bf16_t)v;
    } else if (tid < S1 + S2 + S3 + S4 + NHEADS) {
        int hh = tid - S1 - S2 - S3 - S4;
        asrc[hh] = (hh < 4) ? a1s[hh] : a2s[hh - 4];
        adst[hh] = (hh < 4) ? a1d[hh] : a2d[hh - 4];
    }
}

// ---------------------------------------------------------------------------
// bf16 MFMA GEMM (NT) with fused epilogue:
//   acc = A * Bt^T  (fp32)
//   if bias: v = relu(acc + bias[col]) else v = acc
//   if C : C [row*ldc+col] = v   (fp32), col < ncols, row < N_NODES
//   if Cb: Cb[row*ldc+col] = v   (bf16)
// 128x128 tile, BK=32, 4 waves, 16x16x32 MFMA, global_load_lds staging.
// A has two k-segments (ksplit) to fuse SAGE's mean@Wl + x1@Wr.
// ---------------------------------------------------------------------------
__global__ __launch_bounds__(256) void gemm_bf16(
    const bf16_t* __restrict__ A1, int lda1, int ksplit,
    const bf16_t* __restrict__ A2, int lda2,
    const bf16_t* __restrict__ Bt, int ldb,
    float* __restrict__ C, bf16_t* __restrict__ Cb, long ldc, int K,
    const float* __restrict__ bias, int ncols)
{
    __shared__ bf16_t As[128 * 32];
    __shared__ bf16_t Bs[128 * 32];
    const int tid = threadIdx.x;
    const int wid = tid >> 6, lane = tid & 63;
    const int li = lane & 15, kq = lane >> 4;
    const int wm = (wid >> 1) * 64, wn = (wid & 1) * 64;
    const long r0 = (long)blockIdx.y * 128;
    const int  n0 = blockIdx.x * 128;

    f32x4 acc[4][4] = {};

    const int s0 = wid * 64 + lane;
    const int s1 = 256 + s0;
    const int am0 = s0 >> 2, ak0 = (s0 & 3) ^ ((am0 >> 1) & 3);
    const int am1 = s1 >> 2, ak1 = (s1 & 3) ^ ((am1 >> 1) & 3);
    const int swz = (li >> 1) & 3;

    for (int k0 = 0; k0 < K; k0 += 32) {
        const bf16_t* Ab; int lda;
        if (k0 < ksplit) { Ab = A1 + k0;            lda = lda1; }
        else             { Ab = A2 + (k0 - ksplit); lda = lda2; }
        __builtin_amdgcn_global_load_lds(
            (const __attribute__((address_space(1))) void*)(Ab + (r0 + am0) * (long)lda + ak0 * 8),
            (__attribute__((address_space(3))) void*)(As + (wid * 64) * 8), 16, 0, 0);
        __builtin_amdgcn_global_load_lds(
            (const __attribute__((address_space(1))) void*)(Ab + (r0 + am1) * (long)lda + ak1 * 8),
            (__attribute__((address_space(3))) void*)(As + (256 + wid * 64) * 8), 16, 0, 0);
        __builtin_amdgcn_global_load_lds(
            (const __attribute__((address_space(1))) void*)(Bt + (n0 + am0) * (long)ldb + k0 + ak0 * 8),
            (__attribute__((address_space(3))) void*)(Bs + (wid * 64) * 8), 16, 0, 0);
        __builtin_amdgcn_global_load_lds(
            (const __attribute__((address_space(1))) void*)(Bt + (n0 + am1) * (long)ldb + k0 + ak1 * 8),
            (__attribute__((address_space(3))) void*)(Bs + (256 + wid * 64) * 8), 16, 0, 0);
        __syncthreads();

        bf16x8 a[4], b[4];
#pragma unroll
        for (int f = 0; f < 4; ++f) {
            int m = wm + f * 16 + li;
            a[f] = *(const bf16x8*)(As + m * 32 + ((kq ^ swz) * 8));
            int n = wn + f * 16 + li;
            b[f] = *(const bf16x8*)(Bs + n * 32 + ((kq ^ swz) * 8));
        }
#pragma unroll
        for (int fm = 0; fm < 4; ++fm)
#pragma unroll
            for (int fn = 0; fn < 4; ++fn)
                acc[fm][fn] = __builtin_amdgcn_mfma_f32_16x16x32_bf16(
                    a[fm], b[fn], acc[fm][fn], 0, 0, 0);
        __syncthreads();
    }

    // C/D layout: col = lane&15, row = (lane>>4)*4 + reg
#pragma unroll
    for (int fm = 0; fm < 4; ++fm) {
#pragma unroll
        for (int r = 0; r < 4; ++r) {
            long row = r0 + wm + fm * 16 + kq * 4 + r;
            if (row >= N_NODES) continue;
#pragma unroll
            for (int fn = 0; fn < 4; ++fn) {
                int colg = n0 + wn + fn * 16 + li;
                if (colg >= ncols) continue;
                float v = acc[fm][fn][r];
                if (bias) v = fmaxf(v + bias[colg], 0.f);
                if (C)  C[row * ldc + colg]  = v;
                if (Cb) Cb[row * ldc + colg] = (bf16_t)v;
            }
        }
    }
}

// ---------------------------------------------------------------------------
// GCN aggregation over raw x_bf (384 cols): aggx[i] = x[i]/deg + sum norm*x[s]
// one wave per node; lanes 0..47 own 8 cols each; 2-edge unroll (MLP).
// ---------------------------------------------------------------------------
__global__ __launch_bounds__(64) void agg_x(
    const bf16_t* __restrict__ xb, const int* __restrict__ rowptr,
    const int* __restrict__ col, const float* __restrict__ wcsr,
    const float* __restrict__ dinv, const float* __restrict__ deg,
    bf16_t* __restrict__ aggx)
{
    int i = blockIdx.x;
    int c = threadIdx.x * 8;
    bool act = (c < K1);
    float di = dinv[i];
    float selfw = 1.0f / deg[i];
    float acc0[8] = {}, acc1[8] = {};
    if (act) {
        bf16x8 sv = *(const bf16x8*)(xb + (long)i * K1 + c);
#pragma unroll
        for (int j = 0; j < 8; ++j) acc0[j] = selfw * (float)sv[j];
    }
    int e = rowptr[i], e1 = rowptr[i + 1];
    for (; e + 1 < e1; e += 2) {
        int sA = col[e], sB = col[e + 1];
        float wA = dinv[sA] * wcsr[e] * di;
        float wB = dinv[sB] * wcsr[e + 1] * di;
        if (act) {
            bf16x8 vA = *(const bf16x8*)(xb + (long)sA * K1 + c);
            bf16x8 vB = *(const bf16x8*)(xb + (long)sB * K1 + c);
#pragma unroll
            for (int j = 0; j < 8; ++j) {
                acc0[j] = fmaf(wA, (float)vA[j], acc0[j]);
                acc1[j] = fmaf(wB, (float)vB[j], acc1[j]);
            }
        }
    }
    if (e < e1) {
        int sA = col[e];
        float wA = dinv[sA] * wcsr[e] * di;
        if (act) {
            bf16x8 vA = *(const bf16x8*)(xb + (long)sA * K1 + c);
#pragma unroll
            for (int j = 0; j < 8; ++j) acc0[j] = fmaf(wA, (float)vA[j], acc0[j]);
        }
    }
    if (act) {
        bf16x8 ob;
#pragma unroll
        for (int j = 0; j < 8; ++j) ob[j] = (bf16_t)(acc0[j] + acc1[j]);
        *reinterpret_cast<bf16x8*>(aggx + (long)i * K1 + c) = ob;
    }
}

// ---------------------------------------------------------------------------
// Fused x1 aggregation: ONE gather of x1 rows serves GCN2 (norm-weighted sum
// + self) AND SAGE (plain mean). One wave per node, lane owns 8 of 512 cols.
// ---------------------------------------------------------------------------
__global__ __launch_bounds__(64) void agg_x1(
    const bf16_t* __restrict__ x1b /* dense_bf, cols [0,512) */,
    const int* __restrict__ rowptr, const int* __restrict__ col,
    const float* __restrict__ wcsr, const float* __restrict__ dinv,
    const float* __restrict__ deg, const int* __restrict__ cnt,
    bf16_t* __restrict__ gbf, bf16_t* __restrict__ meanb)
{
    int i = blockIdx.x;
    int c = threadIdx.x * 8;
    float di = dinv[i];
    float selfw = 1.0f / deg[i];
    bf16x8 sv = *(const bf16x8*)(x1b + (long)i * DENSE_F + c);
    float g0[8], g1[8], m0[8], m1[8];
#pragma unroll
    for (int j = 0; j < 8; ++j) {
        g0[j] = selfw * (float)sv[j];
        g1[j] = 0.f; m0[j] = 0.f; m1[j] = 0.f;
    }
    int e = rowptr[i], e1 = rowptr[i + 1];
    for (; e + 1 < e1; e += 2) {
        int sA = col[e], sB = col[e + 1];
        float wA = dinv[sA] * wcsr[e] * di;
        float wB = dinv[sB] * wcsr[e + 1] * di;
        bf16x8 vA = *(const bf16x8*)(x1b + (long)sA * DENSE_F + c);
        bf16x8 vB = *(const bf16x8*)(x1b + (long)sB * DENSE_F + c);
#pragma unroll
        for (int j = 0; j < 8; ++j) {
            float fA = (float)vA[j], fB = (float)vB[j];
            g0[j] = fmaf(wA, fA, g0[j]);
            g1[j] = fmaf(wB, fB, g1[j]);
            m0[j] += fA;
            m1[j] += fB;
        }
    }
    if (e < e1) {
        int sA = col[e];
        float wA = dinv[sA] * wcsr[e] * di;
        bf16x8 vA = *(const bf16x8*)(x1b + (long)sA * DENSE_F + c);
#pragma unroll
        for (int j = 0; j < 8; ++j) {
            float fA = (float)vA[j];
            g0[j] = fmaf(wA, fA, g0[j]);
            m0[j] += fA;
        }
    }
    float inv = 1.0f / fmaxf((float)cnt[i], 1.0f);
    bf16x8 og, om;
#pragma unroll
    for (int j = 0; j < 8; ++j) {
        og[j] = (bf16_t)(g0[j] + g1[j]);
        om[j] = (bf16_t)((m0[j] + m1[j]) * inv);
    }
    *reinterpret_cast<bf16x8*>(gbf   + (long)i * HID + c) = og;
    *reinterpret_cast<bf16x8*>(meanb + (long)i * HID + c) = om;
}

// per-dst GAT attention over CSR (+self loop), softmax shift-free,
// hgat stride HG_LD=32 (3.85 MB, L2-resident), 2-edge unroll
__global__ __launch_bounds__(64) void gat_agg(
    const float* __restrict__ hgat, const int* __restrict__ rowptr,
    const int* __restrict__ col, const float* __restrict__ asrc,
    const float* __restrict__ adst, const float* __restrict__ b1p,
    const float* __restrict__ b2p, float* __restrict__ xout)
{
    int i = blockIdx.x;
    int lane = threadIdx.x;
    int h = (lane < NHEADS) ? lane : 0;
    float hg_i = hgat[(long)i * HG_LD + h];
    float as = asrc[h], ad = adst[h];
    float adhg = ad * hg_i;
    float ev = hg_i * as + adhg;
    ev = ev > 0.f ? ev : 0.2f * ev;
    float ex = __expf(ev);
    float den0 = ex, og0 = ex * hg_i, den1 = 0.f, og1 = 0.f;
    int e = rowptr[i], e1 = rowptr[i + 1];
    for (; e + 1 < e1; e += 2) {
        int sA = col[e], sB = col[e + 1];
        float hA = hgat[(long)sA * HG_LD + h];
        float hB = hgat[(long)sB * HG_LD + h];
        float tA = fmaf(hA, as, adhg); tA = tA > 0.f ? tA : 0.2f * tA;
        float tB = fmaf(hB, as, adhg); tB = tB > 0.f ? tB : 0.2f * tB;
        float xA = __expf(tA), xB = __expf(tB);
        den0 += xA; og0 = fmaf(xA, hA, og0);
        den1 += xB; og1 = fmaf(xB, hB, og1);
    }
    if (e < e1) {
        int sA = col[e];
        float hA = hgat[(long)sA * HG_LD + h];
        float tA = fmaf(hA, as, adhg); tA = tA > 0.f ? tA : 0.2f * tA;
        float xA = __expf(tA);
        den0 += xA; og0 = fmaf(xA, hA, og0);
    }
    float out = (lane < NHEADS) ? (og0 + og1) / (den0 + den1) : 0.f;
    float s4 = out + __shfl_xor(out, 1);
    s4 += __shfl_xor(s4, 2);
    float g0 = __shfl(s4, 0);
    float g1 = __shfl(s4, 4);
    float g2 = __shfl(s4, 8);
    float g3 = __shfl(s4, 12);
    float g4 = __shfl(s4, 16);
    if (lane == 0) {
        float a1 = g0 * 0.25f + b1p[0];
        float a2 = (g1 + g2 + g3 + g4) * 0.0625f + b2p[0];
        xout[i] = 0.5f * (a1 + a2);
    }
}

// ---------------------------------------------------------------------------
extern "C" void kernel_launch(void* const* d_in, const int* in_sizes, int n_in,
                              void* d_out, int out_size, void* d_ws, size_t ws_size,
                              hipStream_t stream) {
    (void)in_sizes; (void)n_in; (void)out_size; (void)ws_size;
    const float* x    = (const float*)d_in[0];
    const int*   ei   = (const int*)d_in[1];
    const float* ew   = (const float*)d_in[2];
    const float* W1   = (const float*)d_in[3];
    const float* b1   = (const float*)d_in[4];
    const float* W2   = (const float*)d_in[5];
    const float* b2   = (const float*)d_in[6];
    const float* sWl  = (const float*)d_in[7];
    const float* sWr  = (const float*)d_in[8];
    const float* sb   = (const float*)d_in[9];
    const float* g1W  = (const float*)d_in[10];
    const float* g1as = (const float*)d_in[11];
    const float* g1ad = (const float*)d_in[12];
    const float* g1b  = (const float*)d_in[13];
    const float* g2W  = (const float*)d_in[14];
    const float* g2as = (const float*)d_in[15];
    const float* g2ad = (const float*)d_in[16];
    const float* g2b  = (const float*)d_in[17];

    const int* src = ei;
    const int* dst = ei + N_EDGES;

    float* xout  = (float*)d_out;          // [N]
    float* dense = xout + N_NODES;         // [N,1536] fp32 (output 2)

    size_t off = 0;
    auto alloc = [&](size_t nbytes) -> void* {
        void* p = (char*)d_ws + off;
        off += (nbytes + 255) & ~(size_t)255;
        return p;
    };
    bf16_t* dense_bf = (bf16_t*)alloc((size_t)M_PAD * DENSE_F * 2);
    bf16_t* x_bf     = (bf16_t*)alloc((size_t)M_PAD * K1 * 2);
    bf16_t* aggx_bf  = (bf16_t*)alloc((size_t)M_PAD * K1 * 2);
    bf16_t* g_bf     = (bf16_t*)alloc((size_t)M_PAD * HID * 2);
    bf16_t* mean_bf  = (bf16_t*)alloc((size_t)M_PAD * HID * 2);
    float*  hgat     = (float*)alloc((size_t)M_PAD * HG_LD * 4);
    bf16_t* W1t      = (bf16_t*)alloc((size_t)512 * K1 * 2);
    bf16_t* W2t      = (bf16_t*)alloc((size_t)512 * 512 * 2);
    bf16_t* Bst      = (bf16_t*)alloc((size_t)512 * 1024 * 2);
    bf16_t* Wgt      = (bf16_t*)alloc((size_t)128 * DENSE_F * 2);
    float*  deg      = (float*)alloc((size_t)N_NODES * 4);
    float*  dinv     = (float*)alloc((size_t)N_NODES * 4);
    float*  asrc     = (float*)alloc(32 * 4);
    float*  adst     = (float*)alloc(32 * 4);
    int*    cnt      = (int*)alloc((size_t)N_NODES * 4);
    int*    rowp     = (int*)alloc((size_t)(N_NODES + 1) * 4);
    int*    woff     = (int*)alloc((size_t)N_NODES * 4);
    int*    colx     = (int*)alloc((size_t)N_EDGES * 4);
    float*  wcsr     = (float*)alloc((size_t)N_EDGES * 4);

    const int EB = (N_EDGES + 255) / 256;
    const int NB = (N_NODES + 255) / 256;

    hipMemsetAsync(deg, 0, (size_t)N_NODES * 4, stream);
    hipMemsetAsync(cnt, 0, (size_t)N_NODES * 4, stream);
    build_stats<<<EB, 256, 0, stream>>>(dst, ew, deg, cnt);
    node_stats<<<NB, 256, 0, stream>>>(deg, dinv);
    scan_rowptr<<<1, 1024, 0, stream>>>(cnt, rowp, woff);
    scatter_csr<<<EB, 256, 0, stream>>>(src, dst, ew, woff, colx, wcsr);

    conv_x<<<(M_PAD * K1 + 255) / 256, 256, 0, stream>>>(x, x_bf);
    pack_weights<<<(S1 + S2 + S3 + S4 + NHEADS + 255) / 256, 256, 0, stream>>>(
        W1, W2, sWl, sWr, g1W, g2W, g1as, g1ad, g2as, g2ad,
        W1t, W2t, Bst, Wgt, asrc, adst);

    const dim3 gB(256);
    const dim3 g512(HID / 128, M_PAD / 128);   // (4, 235)
    const dim3 g128(1, M_PAD / 128);           // (1, 235)

    // GCN1 (commuted): aggx = A_gcn * x ; x1 = relu(aggx@W1 + b1) -> dense[:,0:512]
    agg_x<<<N_NODES, 64, 0, stream>>>(x_bf, rowp, colx, wcsr, dinv, deg, aggx_bf);
    gemm_bf16<<<g512, gB, 0, stream>>>(aggx_bf, K1, K1, aggx_bf, K1, W1t, K1,
                                       dense, dense_bf, DENSE_F, K1, b1, 512);

    // Fused x1 gather: g = A_gcn * x1 (GCN2), mean = mean(x1) (SAGE)
    agg_x1<<<N_NODES, 64, 0, stream>>>(dense_bf, rowp, colx, wcsr, dinv, deg, cnt,
                                       g_bf, mean_bf);
    // GCN2 (commuted): x2 = relu(g@W2 + b2) -> dense[:,512:1024]
    gemm_bf16<<<g512, gB, 0, stream>>>(g_bf, HID, HID, g_bf, HID, W2t, HID,
                                       dense + HID, dense_bf + HID, DENSE_F,
                                       HID, b2, 512);
    // SAGE: x3 = relu([mean|x1]@[Wl;Wr] + sb) -> dense[:,1024:1536]
    gemm_bf16<<<g512, gB, 0, stream>>>(mean_bf, HID, HID, dense_bf, DENSE_F,
                                       Bst, 1024, dense + 2 * HID,
                                       dense_bf + 2 * HID, DENSE_F, 1024, sb, 512);

    // GAT: hgat = dense @ Wg (fp32, masked to 32 cols, stride 32), then aggregate
    gemm_bf16<<<g128, gB, 0, stream>>>(dense_bf, DENSE_F, DENSE_F, dense_bf, DENSE_F,
                                       Wgt, DENSE_F, hgat, nullptr, HG_LD,
                                       DENSE_F, nullptr, HG_LD);
    gat_agg<<<N_NODES, 64, 0, stream>>>(hgat, rowp, colx, asrc, adst, g1b, g2b, xout);
}